// Round 1
// baseline (738.158 us; speedup 1.0000x reference)
//
#include <hip/hip_runtime.h>

typedef __attribute__((ext_vector_type(4))) float f32x4;
typedef __attribute__((ext_vector_type(8))) short s16x8;

#define B_ 64
#define T_ 4096
#define H_ 512
#define E_ 512

__device__ __forceinline__ unsigned short f2bf(float f) {
  unsigned int u = __float_as_uint(f);
  u += 0x7fffu + ((u >> 16) & 1u);
  return (unsigned short)(u >> 16);
}

__device__ __forceinline__ float fast_tanh(float x) {
  // tanh(x) = 1 - 2/(e^{2x}+1); v_exp_f32 computes 2^x
  float e;
  asm("v_exp_f32 %0, %1" : "=v"(e) : "v"(x * 2.88539008177792681f));
  float r;
  asm("v_rcp_f32 %0, %1" : "=v"(r) : "v"(e + 1.0f));
  return 1.0f - 2.0f * r;
}

// k0: W_e (rows 512..1023 of W_attn, [e][h]) -> Wt bf16 [h][e]
__global__ void k0_transpose(const float* __restrict__ W, unsigned short* __restrict__ Wt) {
  __shared__ float tile[16][17];
  int e0 = blockIdx.x * 16, h0 = blockIdx.y * 16;
  int tx = threadIdx.x, ty = threadIdx.y;
  tile[ty][tx] = W[(size_t)(512 + e0 + ty) * H_ + h0 + tx];
  __syncthreads();
  Wt[(size_t)(h0 + ty) * E_ + e0 + tx] = f2bf(tile[tx][ty]);
}

// k1: projb[b][h] = b_attn[h] + sum_e hidden[b][e] * W_attn[e][h]
__global__ void k1_projb(const float* __restrict__ hidden, const float* __restrict__ W,
                         const float* __restrict__ b_attn, float* __restrict__ projb) {
  __shared__ float hid_s[H_];
  int b = blockIdx.x;
  int h = threadIdx.x;  // 512 threads
  hid_s[h] = hidden[b * H_ + h];
  __syncthreads();
  float s = b_attn[h];
  #pragma unroll 8
  for (int e = 0; e < H_; ++e) s = fmaf(hid_s[e], W[(size_t)e * H_ + h], s);
  projb[b * H_ + h] = s;
}

// k2: logits[b][t] = sum_h tanh(projb[b][h] + (enc @ W_e)[b,t,h]) * v_w[h]
// block: 128 T-rows x 512 H, 8 waves (2 T x 4 H), wave tile 64T x 128H
__global__ __launch_bounds__(512, 2) void k2_logits(
    const float* __restrict__ enc, const unsigned short* __restrict__ Wt,
    const float* __restrict__ projb, const float* __restrict__ vw,
    float* __restrict__ logits) {
  __shared__ float projb_s[H_];
  __shared__ float vw_s[H_];
  __shared__ float part[128][4];

  const int b = blockIdx.y;
  const int t0 = blockIdx.x * 128;
  const int tid = threadIdx.x;
  const int lane = tid & 63;
  const int w = tid >> 6;
  const int waveT = w >> 2;  // 0..1
  const int waveH = w & 3;   // 0..3
  const int lr = lane & 15;
  const int lq = lane >> 4;

  projb_s[tid] = projb[b * H_ + tid];
  vw_s[tid] = vw[tid];
  __syncthreads();

  f32x4 acc[4][8];
  #pragma unroll
  for (int a = 0; a < 4; ++a)
    #pragma unroll
    for (int nb = 0; nb < 8; ++nb) {
      f32x4 z = {0.0f, 0.0f, 0.0f, 0.0f};
      acc[a][nb] = z;
    }

  const float* encBase =
      enc + ((size_t)(b * T_ + t0 + waveT * 64 + lr)) * (size_t)E_ + lq * 8;
  const unsigned short* WtBase = Wt + (size_t)(waveH * 128 + lr) * E_ + lq * 8;

  #pragma unroll 2
  for (int kk = 0; kk < E_; kk += 32) {
    s16x8 af[4];
    #pragma unroll
    for (int a = 0; a < 4; ++a) {
      const float* p = encBase + (size_t)(a * 16) * E_ + kk;
      f32x4 v0 = *(const f32x4*)p;
      f32x4 v1 = *(const f32x4*)(p + 4);
      s16x8 t;
      #pragma unroll
      for (int j = 0; j < 4; ++j) {
        t[j] = (short)f2bf(v0[j]);
        t[j + 4] = (short)f2bf(v1[j]);
      }
      af[a] = t;
    }
    s16x8 bfr[8];
    #pragma unroll
    for (int nb = 0; nb < 8; ++nb)
      bfr[nb] = *(const s16x8*)(WtBase + (size_t)(nb * 16) * E_ + kk);
    #pragma unroll
    for (int a = 0; a < 4; ++a)
      #pragma unroll
      for (int nb = 0; nb < 8; ++nb)
        acc[a][nb] = __builtin_amdgcn_mfma_f32_16x16x32_bf16(af[a], bfr[nb], acc[a][nb], 0, 0, 0);
  }

  // epilogue: energy = tanh(acc + projb), logit partial = sum_h energy * vw
  #pragma unroll
  for (int a = 0; a < 4; ++a) {
    #pragma unroll
    for (int j = 0; j < 4; ++j) {
      float s = 0.0f;
      #pragma unroll
      for (int nb = 0; nb < 8; ++nb) {
        const int h = waveH * 128 + nb * 16 + lr;
        float x = acc[a][nb][j] + projb_s[h];
        s += fast_tanh(x) * vw_s[h];
      }
      // reduce across the 16 lanes (lr = h sub-index); t is fixed within each group
      s += __shfl_xor(s, 1);
      s += __shfl_xor(s, 2);
      s += __shfl_xor(s, 4);
      s += __shfl_xor(s, 8);
      if (lr == 0) part[waveT * 64 + a * 16 + lq * 4 + j][waveH] = s;
    }
  }
  __syncthreads();
  if (tid < 128) {
    float s = part[tid][0] + part[tid][1] + part[tid][2] + part[tid][3];
    logits[(size_t)b * T_ + t0 + tid] = s;
  }
}

// k3: softmax over T per batch; writes weights to d_out region 2
__global__ __launch_bounds__(256) void k3_softmax(const float* __restrict__ logits,
                                                  float* __restrict__ weights) {
  __shared__ float red[4];
  const int b = blockIdx.x;
  const int tid = threadIdx.x;
  const float* lg = logits + (size_t)b * T_;
  float v[16];
  float m = -1e30f;
  #pragma unroll
  for (int i = 0; i < 16; ++i) {
    v[i] = lg[tid + i * 256];
    m = fmaxf(m, v[i]);
  }
  #pragma unroll
  for (int d = 1; d < 64; d <<= 1) m = fmaxf(m, __shfl_xor(m, d));
  if ((tid & 63) == 0) red[tid >> 6] = m;
  __syncthreads();
  m = fmaxf(fmaxf(red[0], red[1]), fmaxf(red[2], red[3]));
  __syncthreads();
  float s = 0.0f;
  #pragma unroll
  for (int i = 0; i < 16; ++i) {
    v[i] = __expf(v[i] - m);
    s += v[i];
  }
  #pragma unroll
  for (int d = 1; d < 64; d <<= 1) s += __shfl_xor(s, d);
  if ((tid & 63) == 0) red[tid >> 6] = s;
  __syncthreads();
  s = red[0] + red[1] + red[2] + red[3];
  float inv = 1.0f / s;
  #pragma unroll
  for (int i = 0; i < 16; ++i) weights[(size_t)b * T_ + tid + i * 256] = v[i] * inv;
}

// k4: partial context over T-chunks of 128
__global__ __launch_bounds__(256) void k4_ctx_partial(const float* __restrict__ enc,
                                                      const float* __restrict__ weights,
                                                      float* __restrict__ partial) {
  __shared__ float w_s[128];
  const int b = blockIdx.y;
  const int c = blockIdx.x;  // 32 chunks
  const int tid = threadIdx.x;
  if (tid < 128) w_s[tid] = weights[(size_t)b * T_ + c * 128 + tid];
  __syncthreads();
  const float* ep = enc + ((size_t)(b * T_ + c * 128)) * E_;
  const int e0 = tid * 2;
  float ax = 0.0f, ay = 0.0f;
  #pragma unroll 4
  for (int t = 0; t < 128; ++t) {
    float2 v = *(const float2*)(ep + (size_t)t * E_ + e0);
    float wt = w_s[t];
    ax = fmaf(wt, v.x, ax);
    ay = fmaf(wt, v.y, ay);
  }
  float* pp = partial + (size_t)(b * 32 + c) * E_;
  pp[e0] = ax;
  pp[e0 + 1] = ay;
}

// k5: reduce partials -> context (d_out region 1)
__global__ void k5_ctx_reduce(const float* __restrict__ partial, float* __restrict__ ctx) {
  const int g = blockIdx.x * 256 + threadIdx.x;  // 0..32767
  const int b = g >> 9, e = g & 511;
  const float* pp = partial + (size_t)b * 32 * E_ + e;
  float s = 0.0f;
  #pragma unroll
  for (int c = 0; c < 32; ++c) s += pp[(size_t)c * E_];
  ctx[g] = s;
}

extern "C" void kernel_launch(void* const* d_in, const int* in_sizes, int n_in,
                              void* d_out, int out_size, void* d_ws, size_t ws_size,
                              hipStream_t stream) {
  const float* hidden = (const float*)d_in[0];
  const float* enc = (const float*)d_in[1];
  const float* W_attn = (const float*)d_in[2];
  const float* b_attn = (const float*)d_in[3];
  const float* v_w = (const float*)d_in[4];

  float* out_ctx = (float*)d_out;                  // 64*512
  float* out_w = (float*)d_out + (size_t)B_ * H_;  // 64*4096

  char* ws = (char*)d_ws;
  unsigned short* Wt = (unsigned short*)ws;                               // 512 KiB
  float* projb = (float*)(ws + 512 * 1024);                               // 128 KiB
  float* logits = (float*)(ws + 512 * 1024 + 128 * 1024);                 // 1 MiB
  float* partial = (float*)(ws + 512 * 1024 + 128 * 1024 + 1024 * 1024);  // 4 MiB

  k0_transpose<<<dim3(32, 32), dim3(16, 16), 0, stream>>>(W_attn, Wt);
  k1_projb<<<64, 512, 0, stream>>>(hidden, W_attn, b_attn, projb);
  k2_logits<<<dim3(T_ / 128, B_), 512, 0, stream>>>(enc, Wt, projb, v_w, logits);
  k3_softmax<<<B_, 256, 0, stream>>>(logits, out_w);
  k4_ctx_partial<<<dim3(32, B_), 256, 0, stream>>>(enc, out_w, partial);
  k5_ctx_reduce<<<128, 256, 0, stream>>>(partial, out_ctx);
}

// Round 2
// 432.961 us; speedup vs baseline: 1.7049x; 1.7049x over previous
//
#include <hip/hip_runtime.h>
#include <hip/hip_bf16.h>

typedef __attribute__((ext_vector_type(4))) float f32x4;
typedef __attribute__((ext_vector_type(8))) short s16x8;

#define B_ 64
#define T_ 4096
#define H_ 512
#define E_ 512
#define TB 64  // T-rows per k2 block

__device__ __forceinline__ short b2s(float x) {
  __hip_bfloat16 h = __float2bfloat16(x);  // RNE; compiler fuses pairs to v_cvt_pk_bf16_f32
  return __builtin_bit_cast(short, h);
}

__device__ __forceinline__ s16x8 cvt8(f32x4 a, f32x4 b) {
  s16x8 r;
  r[0] = b2s(a[0]); r[1] = b2s(a[1]); r[2] = b2s(a[2]); r[3] = b2s(a[3]);
  r[4] = b2s(b[0]); r[5] = b2s(b[1]); r[6] = b2s(b[2]); r[7] = b2s(b[3]);
  return r;
}

__device__ __forceinline__ void gload16(const float* g, float* lds) {
  // async global->LDS, 16B/lane; LDS dest = wave-uniform base + lane*16 (linear!)
  __builtin_amdgcn_global_load_lds(
      (const __attribute__((address_space(1))) void*)g,
      (__attribute__((address_space(3))) void*)lds, 16, 0, 0);
}

__device__ __forceinline__ float fast_tanh(float x) {
  float e;
  asm("v_exp_f32 %0, %1" : "=v"(e) : "v"(x * 2.88539008177792681f));  // 2^(2x/ln2)
  float r;
  asm("v_rcp_f32 %0, %1" : "=v"(r) : "v"(e + 1.0f));
  return 1.0f - 2.0f * r;
}

// k0: W_e (rows 512..1023 of W_attn, [e][h]) -> Wt bf16 [h][e]
__global__ void k0_transpose(const float* __restrict__ W, unsigned short* __restrict__ Wt) {
  __shared__ float tile[16][17];
  int e0 = blockIdx.x * 16, h0 = blockIdx.y * 16;
  int tx = threadIdx.x, ty = threadIdx.y;
  tile[ty][tx] = W[(size_t)(512 + e0 + ty) * H_ + h0 + tx];
  __syncthreads();
  Wt[(size_t)(h0 + ty) * E_ + e0 + tx] = (unsigned short)b2s(tile[tx][ty]);
}

// k1: projb[b][h] = b_attn[h] + sum_e hidden[b][e] * W_attn[e][h]
// grid (64 b, 4 hgroup), 512 threads: 128 h-cols x 4 e-slices
__global__ __launch_bounds__(512) void k1_projb(const float* __restrict__ hidden,
                                                const float* __restrict__ W,
                                                const float* __restrict__ b_attn,
                                                float* __restrict__ projb) {
  __shared__ float hid_s[H_];
  __shared__ float part[4][128];
  const int b = blockIdx.x, hg = blockIdx.y;
  const int tid = threadIdx.x;
  const int hl = tid & 127, es = tid >> 7;
  hid_s[tid] = hidden[b * H_ + tid];
  __syncthreads();
  const int h = hg * 128 + hl;
  const float* wp = W + (size_t)(es * 128) * H_ + h;
  float s = 0.0f;
  #pragma unroll 8
  for (int e = 0; e < 128; ++e) s = fmaf(hid_s[es * 128 + e], wp[(size_t)e * H_], s);
  part[es][hl] = s;
  __syncthreads();
  if (es == 0)
    projb[b * H_ + h] = b_attn[h] + part[0][hl] + part[1][hl] + part[2][hl] + part[3][hl];
}

// k2: logits[b][t] = sum_h tanh(projb[b][h] + (enc @ W_e)[b,t,h]) * v_w[h]
// block: 64 T-rows x 512 H, 4 waves (each wave owns a 128-H slice).
// A (enc fp32) staged via global_load_lds, double-buffered, K-step 64.
// LDS swizzle: 16B-chunk index ^= (row&15); applied on the GLOBAL source addr
// at stage time (gload_lds writes linearly) and on the ds_read addr (rule #21).
__global__ __launch_bounds__(256, 2) void k2_logits(
    const float* __restrict__ enc, const unsigned short* __restrict__ Wt,
    const float* __restrict__ projb, const float* __restrict__ vw,
    float* __restrict__ logits) {
  __shared__ float bufA[2][TB * 64];  // 2 x 16 KiB fp32
  __shared__ float projb_s[H_];
  __shared__ float vw_s[H_];
  __shared__ float part[TB][4];

  const int b = blockIdx.y;
  const int t0 = blockIdx.x * TB;
  const int tid = threadIdx.x;
  const int lane = tid & 63;
  const int w = tid >> 6;  // wave id = H-slice
  const int lr = lane & 15;
  const int lq = lane >> 4;

  projb_s[tid] = projb[b * H_ + tid];
  projb_s[tid + 256] = projb[b * H_ + tid + 256];
  vw_s[tid] = vw[tid];
  vw_s[tid + 256] = vw[tid + 256];

  f32x4 acc[4][8] = {};

  const size_t encRow0 = (size_t)(b * T_ + t0);

  // stage K-slice s (64 floats/row) of the 64-row tile into bufA[bi]
  auto stage = [&](int bi, int s) {
    #pragma unroll
    for (int j = 0; j < 4; ++j) {
      const int row = w * 16 + j * 4 + (lane >> 4);       // per-lane row (4 rows/instr)
      const int cg = (lane & 15) ^ (row & 15);            // pre-swizzled source chunk
      const float* g = enc + (encRow0 + row) * (size_t)E_ + s * 64 + cg * 4;
      gload16(g, &bufA[bi][(w * 16 + j * 4) * 64]);       // uniform LDS base, linear dest
    }
  };

  const unsigned short* WtBase = Wt + (size_t)(w * 128 + lr) * E_ + lq * 8;

  stage(0, 0);
  __syncthreads();  // drains vmcnt (gload_lds) + lgkmcnt (projb_s/vw_s writes)

  int cur = 0;
  for (int s = 0; s < 8; ++s) {
    if (s < 7) stage(cur ^ 1, s + 1);  // issue next-tile loads BEFORE compute
    #pragma unroll
    for (int sub = 0; sub < 2; ++sub) {
      s16x8 bfr[8];
      #pragma unroll
      for (int nb = 0; nb < 8; ++nb)
        bfr[nb] = *(const s16x8*)(WtBase + ((size_t)nb * 16) * E_ + s * 64 + sub * 32);
      s16x8 af[4];
      #pragma unroll
      for (int a = 0; a < 4; ++a) {
        const float* base = &bufA[cur][(a * 16 + lr) * 64];
        const int c0 = sub * 8 + lq * 2;
        f32x4 f0 = *(const f32x4*)(base + ((c0 ^ lr) * 4));        // swizzled read
        f32x4 f1 = *(const f32x4*)(base + (((c0 + 1) ^ lr) * 4));
        af[a] = cvt8(f0, f1);
      }
      #pragma unroll
      for (int a = 0; a < 4; ++a)
        #pragma unroll
        for (int nb = 0; nb < 8; ++nb)
          acc[a][nb] =
              __builtin_amdgcn_mfma_f32_16x16x32_bf16(af[a], bfr[nb], acc[a][nb], 0, 0, 0);
    }
    __syncthreads();  // one drain per K-step (stage done + reads done)
    cur ^= 1;
  }

  // epilogue: energy = tanh(acc + projb), logit partial = sum_h energy * vw
  #pragma unroll
  for (int a = 0; a < 4; ++a) {
    #pragma unroll
    for (int j = 0; j < 4; ++j) {
      float ssum = 0.0f;
      #pragma unroll
      for (int nb = 0; nb < 8; ++nb) {
        const int h = w * 128 + nb * 16 + lr;  // C/D: col = lane&15
        float x = acc[a][nb][j] + projb_s[h];
        ssum += fast_tanh(x) * vw_s[h];
      }
      ssum += __shfl_xor(ssum, 1);
      ssum += __shfl_xor(ssum, 2);
      ssum += __shfl_xor(ssum, 4);
      ssum += __shfl_xor(ssum, 8);
      if (lr == 0) part[a * 16 + lq * 4 + j][w] = ssum;  // C/D: row = lq*4 + j
    }
  }
  __syncthreads();
  if (tid < TB)
    logits[(size_t)b * T_ + t0 + tid] = part[tid][0] + part[tid][1] + part[tid][2] + part[tid][3];
}

// k3: softmax over T per batch; writes weights
__global__ __launch_bounds__(256) void k3_softmax(const float* __restrict__ logits,
                                                  float* __restrict__ weights) {
  __shared__ float red[4];
  const int b = blockIdx.x;
  const int tid = threadIdx.x;
  const float* lg = logits + (size_t)b * T_;
  float v[16];
  float m = -1e30f;
  #pragma unroll
  for (int i = 0; i < 16; ++i) {
    v[i] = lg[tid + i * 256];
    m = fmaxf(m, v[i]);
  }
  #pragma unroll
  for (int d = 1; d < 64; d <<= 1) m = fmaxf(m, __shfl_xor(m, d));
  if ((tid & 63) == 0) red[tid >> 6] = m;
  __syncthreads();
  m = fmaxf(fmaxf(red[0], red[1]), fmaxf(red[2], red[3]));
  __syncthreads();
  float s = 0.0f;
  #pragma unroll
  for (int i = 0; i < 16; ++i) {
    v[i] = __expf(v[i] - m);
    s += v[i];
  }
  #pragma unroll
  for (int d = 1; d < 64; d <<= 1) s += __shfl_xor(s, d);
  if ((tid & 63) == 0) red[tid >> 6] = s;
  __syncthreads();
  s = red[0] + red[1] + red[2] + red[3];
  float inv = 1.0f / s;
  #pragma unroll
  for (int i = 0; i < 16; ++i) weights[(size_t)b * T_ + tid + i * 256] = v[i] * inv;
}

// k4: partial context over T-chunks of 64; 256 thr = 128 e-vec4 x 2 t-halves
__global__ __launch_bounds__(256) void k4_ctx_partial(const float* __restrict__ enc,
                                                      const float* __restrict__ weights,
                                                      float* __restrict__ partial) {
  __shared__ float w_s[64];
  __shared__ f32x4 comb[128];
  const int b = blockIdx.y, c = blockIdx.x;
  const int tid = threadIdx.x;
  const int p = tid >> 7, el = tid & 127;
  if (tid < 64) w_s[tid] = weights[(size_t)b * T_ + c * 64 + tid];
  __syncthreads();
  const float* ep = enc + ((size_t)(b * T_ + c * 64 + p * 32)) * E_ + el * 4;
  f32x4 a0 = {}, a1 = {};
  #pragma unroll 8
  for (int t = 0; t < 32; t += 2) {
    a0 += w_s[p * 32 + t] * (*(const f32x4*)(ep + (size_t)t * E_));
    a1 += w_s[p * 32 + t + 1] * (*(const f32x4*)(ep + (size_t)(t + 1) * E_));
  }
  f32x4 ssum = a0 + a1;
  if (p == 1) comb[el] = ssum;
  __syncthreads();
  if (p == 0) {
    f32x4 r = ssum + comb[el];
    *(f32x4*)(partial + ((size_t)(b * 64 + c)) * E_ + el * 4) = r;
  }
}

// k5: reduce 64 partials -> context
__global__ void k5_ctx_reduce(const float* __restrict__ partial, float* __restrict__ ctx) {
  const int g = blockIdx.x * 256 + threadIdx.x;  // 8192 vec4s
  const int b = g >> 7, v = g & 127;
  const float* pp = partial + (size_t)b * 64 * E_ + v * 4;
  f32x4 s = {};
  #pragma unroll 8
  for (int c = 0; c < 64; ++c) s += *(const f32x4*)(pp + (size_t)c * E_);
  *(f32x4*)(ctx + (size_t)b * E_ + v * 4) = s;
}

extern "C" void kernel_launch(void* const* d_in, const int* in_sizes, int n_in,
                              void* d_out, int out_size, void* d_ws, size_t ws_size,
                              hipStream_t stream) {
  const float* hidden = (const float*)d_in[0];
  const float* enc = (const float*)d_in[1];
  const float* W_attn = (const float*)d_in[2];
  const float* b_attn = (const float*)d_in[3];
  const float* v_w = (const float*)d_in[4];

  float* out_ctx = (float*)d_out;                  // 64*512
  float* out_w = (float*)d_out + (size_t)B_ * H_;  // 64*4096

  char* ws = (char*)d_ws;
  unsigned short* Wt = (unsigned short*)ws;             // 512 KiB
  float* projb = (float*)(ws + (512 << 10));            // 128 KiB
  float* logits = (float*)(ws + (640 << 10));           // 1 MiB
  float* partial = (float*)(ws + (1664 << 10));         // 8 MiB

  k0_transpose<<<dim3(32, 32), dim3(16, 16), 0, stream>>>(W_attn, Wt);
  k1_projb<<<dim3(64, 4), 512, 0, stream>>>(hidden, W_attn, b_attn, projb);
  k2_logits<<<dim3(T_ / TB, B_), 256, 0, stream>>>(enc, Wt, projb, v_w, logits);
  k3_softmax<<<B_, 256, 0, stream>>>(logits, out_w);
  k4_ctx_partial<<<dim3(64, B_), 256, 0, stream>>>(enc, out_w, partial);
  k5_ctx_reduce<<<32, 256, 0, stream>>>(partial, out_ctx);
}